// Round 10
// baseline (94.716 us; speedup 1.0000x reference)
//
#include <hip/hip_runtime.h>

#define H_DIM 256
#define N2D   32
#define L_SEQ 4096
#define B_SZ  16
#define L_C   128
#define N_C   32
#define KPAD  136

typedef short short8 __attribute__((ext_vector_type(8)));
typedef short short4v __attribute__((ext_vector_type(4)));
typedef float f32x4  __attribute__((ext_vector_type(4)));
typedef unsigned short ushort;

__device__ __forceinline__ ushort f2bf(float f) {
  unsigned int u = __float_as_uint(f);
  u = (u + 0x7fffu + ((u >> 16) & 1u)) >> 16;
  return (ushort)u;
}
__device__ __forceinline__ float bf2f(ushort s) {
  return __uint_as_float(((unsigned int)s) << 16);
}

// Merged front-end, block-range dispatch (2624 blocks x 256 thr):
//   [0,256)    : k_prep body (h = bid)
//   [256,576)  : w-prep (convw <64 blocks, wprep else). W2 repacked with
//                PERMUTED output columns: srow = (g>>2)*64 + (l&15)*4 + (g&3)
//   [576,2624) : x transpose (B,L,H) fp32 -> U (H, B*L) bf16
__global__ __launch_bounds__(256) void k_front(
    const float* __restrict__ x, const float* __restrict__ log_dt,
    const float* __restrict__ log_A_real, const float* __restrict__ A_imag,
    const float* __restrict__ C_re, const float* __restrict__ C_im,
    const float* __restrict__ W1, const float* __restrict__ W2,
    const float* __restrict__ gam, const float* __restrict__ bet,
    const float* __restrict__ b1, float* __restrict__ parK,
    ushort* __restrict__ Mb, ushort* __restrict__ Lb,
    ushort* __restrict__ w1f, ushort* __restrict__ w2f,
    float* __restrict__ cs1, float* __restrict__ b1p,
    ushort* __restrict__ U) {
  int bid = blockIdx.x;
  int t = threadIdx.x;
  if (bid < 256) {
    int h = bid;
    __shared__ float sdre[32], sdim[32], scdr[32], scdi[32], slr[32], sli[32];
    if (t < 32) {
      int i = h * 32 + t;
      float dt = expf(log_dt[h]);
      float ar = -expf(log_A_real[i]);
      float ai = A_imag[i];
      float dre = ar * dt, dim = ai * dt;
      float er = expf(dre), sn, cs;
      sincosf(dim, &sn, &cs);
      float lr = er * cs, li = er * sn;
      float nr = lr - 1.f, ni = li;
      float inv = 1.f / (ar * ar + ai * ai);
      float tr = (nr * ar + ni * ai) * inv, ti = (ni * ar - nr * ai) * inv;
      float cdr = C_re[i] * tr - C_im[i] * ti;
      float cdi = C_re[i] * ti + C_im[i] * tr;
      sdre[t] = dre; sdim[t] = dim; scdr[t] = cdr; scdi[t] = cdi;
      slr[t] = lr; sli[t] = li;
      float e1 = expf(128.f * dre), ph = 128.f * dim;
      sincosf(ph, &sn, &cs);
      parK[i] = e1 * cs;
      parK[8192 + i] = e1 * sn;
    }
    __syncthreads();
    if (t < 128) {
      float ksum = 0.f;
      float tf = (float)t;
      for (int n = 0; n < 32; ++n) {
        float e = expf(tf * sdre[n]);
        float sn, cs;
        sincosf(tf * sdim[n], &sn, &cs);
        float pr = e * cs, pi = e * sn;  // lam^t
        ksum = fmaf(scdr[n], pr, fmaf(-scdi[n], pi, ksum));
        Lb[((size_t)h * 64 + 2 * n) * 128 + (127 - t)] = f2bf(pr);
        Lb[((size_t)h * 64 + 2 * n + 1) * 128 + (127 - t)] = f2bf(pi);
        float plr = pr * slr[n] - pi * sli[n];
        float pli = pr * sli[n] + pi * slr[n];  // lam^{t+1}
        Mb[((size_t)h * 128 + t) * 64 + 2 * n] =
            f2bf(2.f * (scdr[n] * plr - scdi[n] * pli));
        Mb[((size_t)h * 128 + t) * 64 + 2 * n + 1] =
            f2bf(-2.f * (scdr[n] * pli + scdi[n] * plr));
      }
      parK[16384 + h * 128 + t] = 2.f * ksum;
    }
  } else if (bid < 576) {
    int wb = bid - 256;
    if (wb < 64) {
      int i = wb * 256 + t;  // 16384 threads
      int mat = i >> 13;
      int fi = i & 8191;  // ((kk*16+g)*64 + l)
      int l = fi & 63;
      int gk = fi >> 6;
      int g = gk & 15, kk = gk >> 4;
      int srow = mat ? ((g >> 2) * 64 + (l & 15) * 4 + (g & 3))
                     : (g * 16 + (l & 15));
      int scol = kk * 32 + ((l >> 4) << 3);
      const float* W = mat ? W2 : W1;
      ushort* out = mat ? w2f : w1f;
      short8 v;
#pragma unroll
      for (int e = 0; e < 8; ++e) {
        float w = W[(size_t)srow * 256 + scol + e];
        if (!mat) w *= gam[scol + e];
        v[e] = (short)f2bf(w);
      }
      *(short8*)&out[(size_t)fi * 8] = v;
    } else {
      int o = wb - 64;
      __shared__ float ra[256], rb[256];
      float w = W1[(size_t)o * 256 + t];
      ra[t] = bf2f(f2bf(w * gam[t]));
      rb[t] = w * bet[t];
      __syncthreads();
      for (int s = 128; s > 0; s >>= 1) {
        if (t < s) { ra[t] += ra[t + s]; rb[t] += rb[t + s]; }
        __syncthreads();
      }
      if (t == 0) { cs1[o] = ra[0]; b1p[o] = b1[o] + rb[0]; }
    }
  } else {
    int blk = bid - 576;  // 2048
    int b = blk >> 7;
    int l0 = (blk & 127) << 5;
    __shared__ float tile[32][257];
#pragma unroll 8
    for (int r = 0; r < 32; ++r)
      tile[r][t] = x[((size_t)b * L_SEQ + l0 + r) * H_DIM + t];
    __syncthreads();
    int hq = t >> 2, ls = (t & 3) * 8;
#pragma unroll
    for (int pass = 0; pass < 4; ++pass) {
      int h = pass * 64 + hq;
      short8 v;
#pragma unroll
      for (int j = 0; j < 8; ++j) v[j] = (short)f2bf(tile[ls + j][h]);
      *(short8*)&U[(size_t)h * 65536 + (size_t)b * L_SEQ + l0 + ls] = v;
    }
  }
}

// FUSED states + scan + y — 8-wave (4M x 2N) retile: same LDS (2 blk/CU),
// same staging bytes, same barrier count, same per-element MFMA sequence
// (bit-identical y); per-wave fragments halved -> 16 waves/CU (2x occupancy).
__global__ __launch_bounds__(512, 4) void k_sy(
    const ushort* __restrict__ U, const ushort* __restrict__ Lb,
    const float* __restrict__ parK, const ushort* __restrict__ Mb,
    const float* __restrict__ Dp, ushort* __restrict__ Uo) {
  int wgid = (blockIdx.x & 7) * 128 + (blockIdx.x >> 3);  // bijective, 1024
  int h = wgid >> 2, ct = wgid & 3;
  int t = threadIdx.x;                   // 512 threads = 8 waves
  int lane = t & 63, wid = t >> 6;
  int wm = wid & 3, wn = wid >> 2;       // 4M x 2N
  int lr_ = lane & 15, lk = (lane >> 4) << 3;
  __shared__ ushort Bt[128][KPAD];                       // U tile, whole kernel
  __shared__ __attribute__((aligned(16))) ushort ovl[18432];  // 36 KiB union
  __shared__ float Krow[128];
  ushort (*sts)[72] = (ushort(*)[72])ovl;                // states (pad-72)
  ushort (*M_lds)[72] = (ushort(*)[72])(ovl + 128 * 72); // M (pad-72)
  ushort (*T_lds)[136] = (ushort(*)[136])ovl;            // phase-2 overlay
  if (t < 128) {
    float kv = parK[16384 + h * 128 + t];
    if (t == 0) kv += Dp[h];
    Krow[t] = kv;
  }
#pragma unroll
  for (int q = 0; q < 4; ++q) {
    int idx = q * 512 + t;
    int cc = idx >> 4, seg = idx & 15;
    int col = ct * 128 + cc;
    int b = col >> 5, c = col & 31;
    *(short8*)&Bt[cc][seg * 8] = *(const short8*)&U[
        (size_t)h * 65536 + (size_t)b * L_SEQ + c * L_C + seg * 8];
  }
#pragma unroll
  for (int q = 0; q < 2; ++q) {
    int idx = q * 512 + t;
    int r = idx >> 3, seg = idx & 7;
    *(short8*)&M_lds[r][seg * 8] =
        *(const short8*)&Mb[((size_t)h * 128 + r) * 64 + seg * 8];
  }
  __syncthreads();
  // ---- state-MFMA: local chunk states ----
  {
    f32x4 acc2[2][2];
#pragma unroll
    for (int m = 0; m < 2; ++m)
#pragma unroll
      for (int n = 0; n < 2; ++n) acc2[m][n] = (f32x4){0.f, 0.f, 0.f, 0.f};
#pragma unroll
    for (int ks = 0; ks < 4; ++ks) {
      int k0 = ks * 32;
      short8 a[2], bfr[2];
#pragma unroll
      for (int m = 0; m < 2; ++m)
        a[m] = *(const short8*)&Bt[wm * 32 + m * 16 + lr_][k0 + lk];
#pragma unroll
      for (int n = 0; n < 2; ++n)
        bfr[n] = *(const short8*)&Lb[
            ((size_t)h * 64 + wn * 32 + n * 16 + lr_) * 128 + k0 + lk];
#pragma unroll
      for (int m = 0; m < 2; ++m)
#pragma unroll
        for (int n = 0; n < 2; ++n)
          acc2[m][n] = __builtin_amdgcn_mfma_f32_16x16x32_bf16(
              a[m], bfr[n], acc2[m][n], 0, 0, 0);
    }
#pragma unroll
    for (int m = 0; m < 2; ++m)
#pragma unroll
      for (int n = 0; n < 2; ++n)
#pragma unroll
        for (int jj = 0; jj < 4; ++jj) {
          int rowl = wm * 32 + m * 16 + (lane >> 4) * 4 + jj;  // local 0..127
          int col2n = wn * 32 + n * 16 + (lane & 15);
          sts[rowl][col2n] = f2bf(acc2[m][n][jj]);
        }
  }
  __syncthreads();
  // ---- exclusive scan over this ct-tile's 4 batches (verbatim) ----
  if (t < 128) {
    int n = t & 31, bl = t >> 5;  // local batch 0..3
    float Lr = parK[h * 32 + n], Li = parK[8192 + h * 32 + n];
    float cr = 0.f, ci = 0.f;
#pragma unroll
    for (int c = 0; c < N_C; ++c) {
      int rowl = bl * 32 + c;
      uint* p = (uint*)&sts[rowl][2 * n];
      uint v = *p;
      float fr = bf2f((ushort)(v & 0xffff));
      float fi = bf2f((ushort)(v >> 16));
      *p = (uint)f2bf(cr) | ((uint)f2bf(ci) << 16);
      float nr_ = fmaf(Lr, cr, fmaf(-Li, ci, fr));
      float ni_ = fmaf(Lr, ci, fmaf(Li, cr, fi));
      cr = nr_; ci = ni_;
    }
  }
  __syncthreads();
  // ---- phase 1: acc = s_init @ M (K=64) ----
  f32x4 acc[2][4];
#pragma unroll
  for (int m = 0; m < 2; ++m)
#pragma unroll
    for (int n = 0; n < 4; ++n) acc[m][n] = (f32x4){0.f, 0.f, 0.f, 0.f};
#pragma unroll
  for (int ks = 0; ks < 2; ++ks) {
    int k0 = ks * 32;
    short8 a[2], bfr[4];
#pragma unroll
    for (int m = 0; m < 2; ++m)
      a[m] = *(const short8*)&sts[wm * 32 + m * 16 + lr_][k0 + lk];
#pragma unroll
    for (int n = 0; n < 4; ++n)
      bfr[n] = *(const short8*)&M_lds[wn * 64 + n * 16 + lr_][k0 + lk];
#pragma unroll
    for (int m = 0; m < 2; ++m)
#pragma unroll
      for (int n = 0; n < 4; ++n)
        acc[m][n] = __builtin_amdgcn_mfma_f32_16x16x32_bf16(a[m], bfr[n],
                                                            acc[m][n], 0, 0, 0);
  }
  __syncthreads();  // sts + M dead; T overlays
  // ---- build T in LDS from Krow ----
#pragma unroll
  for (int q = 0; q < 4; ++q) {
    int idx = q * 512 + t;
    int r = idx >> 4, seg = idx & 15;
    short8 v;
#pragma unroll
    for (int e = 0; e < 8; ++e) {
      int d = r - (seg * 8 + e);
      float f = (d >= 0) ? Krow[d] : 0.f;
      v[e] = (short)f2bf(f);
    }
    *(short8*)&T_lds[r][seg * 8] = v;
  }
  __syncthreads();
  // ---- phase 2: acc += u @ T (K=128) ----
#pragma unroll
  for (int ks = 0; ks < 4; ++ks) {
    int k0 = ks * 32;
    short8 a[2], bfr[4];
#pragma unroll
    for (int m = 0; m < 2; ++m)
      a[m] = *(const short8*)&Bt[wm * 32 + m * 16 + lr_][k0 + lk];
#pragma unroll
    for (int n = 0; n < 4; ++n)
      bfr[n] = *(const short8*)&T_lds[wn * 64 + n * 16 + lr_][k0 + lk];
#pragma unroll
    for (int m = 0; m < 2; ++m)
#pragma unroll
      for (int n = 0; n < 4; ++n)
        acc[m][n] = __builtin_amdgcn_mfma_f32_16x16x32_bf16(a[m], bfr[n],
                                                            acc[m][n], 0, 0, 0);
  }
  // ---- stage y into Bt (dead), vectorized short8 store (in place) ----
  __syncthreads();
#pragma unroll
  for (int m = 0; m < 2; ++m) {
    int rowl = wm * 32 + m * 16 + (lane >> 4) * 4;
#pragma unroll
    for (int jj = 0; jj < 4; ++jj) {
      int row = rowl + jj;
#pragma unroll
      for (int n = 0; n < 4; ++n) {
        int lp = wn * 64 + n * 16 + (lane & 15);
        Bt[row][lp] = f2bf(acc[m][n][jj]);
      }
    }
  }
  __syncthreads();
#pragma unroll
  for (int q = 0; q < 4; ++q) {
    int idx = q * 512 + t;
    int r = idx >> 4, seg = idx & 15;
    int col = ct * 128 + r;
    int b = col >> 5, c = col & 31;
    *(short8*)&Uo[(size_t)h * 65536 + (size_t)b * L_SEQ + c * L_C + seg * 8] =
        *(const short8*)&Bt[r][seg * 8];
  }
}

// Fused LN + MLP — round-5 version (measured 48.0 us, banked). Unchanged.
__global__ __launch_bounds__(512, 4) void k_mlp(
    const ushort* __restrict__ U, const ushort* __restrict__ w1f,
    const ushort* __restrict__ w2f, const float* __restrict__ cs1,
    const float* __restrict__ b1p, const float* __restrict__ b2,
    const float* __restrict__ xres, float* __restrict__ outp) {
  int m0 = blockIdx.x << 7;  // 512 blocks x 128 rows of (B*L)
  int t = threadIdx.x;       // 512 threads = 8 waves (2M x 4N)
  int lane = t & 63, wid = t >> 6;
  int wm = wid & 1, wn = wid >> 1;
  int lr_ = lane & 15, lk = (lane >> 4) << 3;
  __shared__ ushort smem[33792];  // yt[128][264] swizzled; c_s overlays [0,32768)
  __shared__ float redA[128][4], redB[128][4];
  __shared__ float mu_s[128], rs_s[128];
  // ---- transpose load: U[h][m0+m] -> yt[m][h ^ ((m>>3&7)<<3)] ----
  {
    int hseg = t >> 4, l16 = t & 15;
    int sw = (l16 & 7) << 3;
#pragma unroll
    for (int p = 0; p < 8; ++p) {
      int h = p * 32 + hseg;
      short8 v = *(const short8*)&U[(size_t)h * 65536 + m0 + l16 * 8];
      int hx = h ^ sw;
#pragma unroll
      for (int e = 0; e < 8; ++e)
        smem[(l16 * 8 + e) * 264 + hx] = (ushort)v[e];
    }
  }
  __syncthreads();
  // ---- LN stats ----
  {
    int rl = t >> 2, q = (t & 3) << 6;
    float s = 0.f, s2 = 0.f;
#pragma unroll
    for (int e = 0; e < 64; e += 8) {
      short8 v = *(const short8*)&smem[rl * 264 + q + e];
#pragma unroll
      for (int j = 0; j < 8; ++j) {
        float f = bf2f((ushort)v[j]);
        s += f;
        s2 = fmaf(f, f, s2);
      }
    }
    redA[rl][t & 3] = s;
    redB[rl][t & 3] = s2;
  }
  __syncthreads();
  if (t < 128) {
    float ss = redA[t][0] + redA[t][1] + redA[t][2] + redA[t][3];
    float ss2 = redB[t][0] + redB[t][1] + redB[t][2] + redB[t][3];
    float mu = ss * (1.f / 256.f);
    float var = fmaf(ss2, 1.f / 256.f, -mu * mu);
    mu_s[t] = mu;
    rs_s[t] = rsqrtf(var + 1e-5f);
  }
  __syncthreads();
  // ---- phase 1: acc = y @ (W1*g)^T ----
  f32x4 acc[4][4];
#pragma unroll
  for (int m = 0; m < 4; ++m)
#pragma unroll
    for (int n = 0; n < 4; ++n) acc[m][n] = (f32x4){0.f, 0.f, 0.f, 0.f};
#pragma unroll
  for (int kabs = 0; kabs < 8; ++kabs) {
    short8 af[4], bfr[4];
#pragma unroll
    for (int n = 0; n < 4; ++n)
      bfr[n] = *(const short8*)&w1f[(((size_t)kabs * 16 + wn * 4 + n) * 64 +
                                     lane) * 8];
#pragma unroll
    for (int m = 0; m < 4; ++m) {
      int row = wm * 64 + m * 16 + lr_;
      int sw = ((row >> 3) & 7) << 3;
      af[m] = *(const short8*)&smem[row * 264 + ((kabs * 32 + lk) ^ sw)];
    }
#pragma unroll
    for (int m = 0; m < 4; ++m)
#pragma unroll
      for (int n = 0; n < 4; ++n)
        acc[m][n] = __builtin_amdgcn_mfma_f32_16x16x32_bf16(af[m], bfr[n],
                                                            acc[m][n], 0, 0, 0);
  }
  __syncthreads();  // yt dead; c_s overlays
  // ---- epilogue 1: LN-correct + bias + relu -> bf16 -> swizzled c_s ----
  int prow = (lane >> 4) << 2;
  int pcol = lane & 15;
#pragma unroll
  for (int n = 0; n < 4; ++n) {
    int gcol = wn * 64 + n * 16 + pcol;
    float c1v = cs1[gcol], b1v = b1p[gcol];
#pragma unroll
    for (int m = 0; m < 4; ++m) {
      int rbase = wm * 64 + m * 16 + prow;
#pragma unroll
      for (int j = 0; j < 4; ++j) {
        int row = rbase + j;
        float v = fmaxf(
            fmaf(rs_s[row], acc[m][n][j] - mu_s[row] * c1v, b1v), 0.f);
        int byte = ((row << 9) + (gcol << 1)) ^ ((row & 7) << 4);
        smem[byte >> 1] = f2bf(v);
        acc[m][n][j] = 0.f;  // re-zero for phase 2
      }
    }
  }
  __syncthreads();
  // ---- phase 2: acc = C1 @ W2^T (W2 output cols permuted at pack time) ----
#pragma unroll
  for (int kabs = 0; kabs < 8; ++kabs) {
    short8 af[4], bfr[4];
#pragma unroll
    for (int n = 0; n < 4; ++n)
      bfr[n] = *(const short8*)&w2f[(((size_t)kabs * 16 + wn * 4 + n) * 64 +
                                     lane) * 8];
#pragma unroll
    for (int m = 0; m < 4; ++m) {
      int row = wm * 64 + m * 16 + lr_;
      int byte = ((row << 9) + ((kabs * 32 + lk) << 1)) ^ ((row & 7) << 4);
      af[m] = *(const short8*)&smem[byte >> 1];
    }
#pragma unroll
    for (int m = 0; m < 4; ++m)
#pragma unroll
      for (int n = 0; n < 4; ++n)
        acc[m][n] = __builtin_amdgcn_mfma_f32_16x16x32_bf16(af[m], bfr[n],
                                                            acc[m][n], 0, 0, 0);
  }
  // ---- epilogue 2: lane owns cols wn*64 + pcol*4 + {0..3} -> float4 IO ----
  f32x4 bv2q = *(const f32x4*)&b2[wn * 64 + pcol * 4];
#pragma unroll
  for (int m = 0; m < 4; ++m) {
#pragma unroll
    for (int j = 0; j < 4; ++j) {
      int grow = m0 + wm * 64 + m * 16 + prow + j;
      size_t base = (size_t)grow * 256 + wn * 64 + pcol * 4;
      f32x4 xr = *(const f32x4*)&xres[base];
      f32x4 o;
#pragma unroll
      for (int n = 0; n < 4; ++n)
        o[n] = xr[n] + fmaxf(acc[m][n][j] + bv2q[n], 0.f);
      *(f32x4*)&outp[base] = o;
    }
  }
}

extern "C" void kernel_launch(void* const* d_in, const int* in_sizes, int n_in,
                              void* d_out, int out_size, void* d_ws, size_t ws_size,
                              hipStream_t stream) {
  const float* x          = (const float*)d_in[0];
  const float* log_dt     = (const float*)d_in[1];
  const float* log_A_real = (const float*)d_in[2];
  const float* A_imag     = (const float*)d_in[3];
  const float* C_re       = (const float*)d_in[4];
  const float* C_im       = (const float*)d_in[5];
  const float* Dp         = (const float*)d_in[6];
  const float* ln_g       = (const float*)d_in[7];
  const float* ln_b       = (const float*)d_in[8];
  const float* W1         = (const float*)d_in[9];
  const float* b1         = (const float*)d_in[10];
  const float* W2         = (const float*)d_in[11];
  const float* b2         = (const float*)d_in[12];

  char* ws = (char*)d_ws;
  float* parK = (float*)ws;                       // 192 KiB
  float* cs1  = (float*)(ws + 0x30000);           // 1 KiB
  float* b1p  = (float*)(ws + 0x30400);           // 1 KiB
  ushort* w1f = (ushort*)(ws + 0x40000);          // 128 KiB (fragment order)
  ushort* w2f = (ushort*)(ws + 0x60000);          // 128 KiB (fragment order)
  ushort* Mb  = (ushort*)(ws + 0x80000);          // 4 MiB
  ushort* Lb  = (ushort*)(ws + 0x480000);         // 4 MiB
  ushort* U   = (ushort*)(ws + 0x2080000);        // 32 MiB (y written in place)

  k_front<<<2624, 256, 0, stream>>>(x, log_dt, log_A_real, A_imag, C_re, C_im,
                                    W1, W2, ln_g, ln_b, b1, parK, Mb, Lb,
                                    w1f, w2f, cs1, b1p, U);
  k_sy<<<1024, 512, 0, stream>>>(U, Lb, parK, Mb, Dp, U);
  k_mlp<<<512, 512, 0, stream>>>(U, w1f, w2f, cs1, b1p, b2, x,
                                 (float*)d_out);
}

// Round 11
// 93.058 us; speedup vs baseline: 1.0178x; 1.0178x over previous
//
#include <hip/hip_runtime.h>

#define H_DIM 256
#define N2D   32
#define L_SEQ 4096
#define B_SZ  16
#define L_C   128
#define N_C   32
#define KPAD  136

typedef short short8 __attribute__((ext_vector_type(8)));
typedef short short4v __attribute__((ext_vector_type(4)));
typedef float f32x4  __attribute__((ext_vector_type(4)));
typedef unsigned short ushort;

__device__ __forceinline__ ushort f2bf(float f) {
  unsigned int u = __float_as_uint(f);
  u = (u + 0x7fffu + ((u >> 16) & 1u)) >> 16;
  return (ushort)u;
}
__device__ __forceinline__ float bf2f(ushort s) {
  return __uint_as_float(((unsigned int)s) << 16);
}

// Merged front-end, block-range dispatch (2624 blocks x 256 thr):
//   [0,256)    : k_prep body (h = bid)
//   [256,576)  : w-prep (convw <64 blocks, wprep else). W2 repacked with
//                PERMUTED output columns: srow = (g>>2)*64 + (l&15)*4 + (g&3)
//   [576,2624) : x transpose (B,L,H) fp32 -> U (H, B*L) bf16
__global__ __launch_bounds__(256) void k_front(
    const float* __restrict__ x, const float* __restrict__ log_dt,
    const float* __restrict__ log_A_real, const float* __restrict__ A_imag,
    const float* __restrict__ C_re, const float* __restrict__ C_im,
    const float* __restrict__ W1, const float* __restrict__ W2,
    const float* __restrict__ gam, const float* __restrict__ bet,
    const float* __restrict__ b1, float* __restrict__ parK,
    ushort* __restrict__ Mb, ushort* __restrict__ Lb,
    ushort* __restrict__ w1f, ushort* __restrict__ w2f,
    float* __restrict__ cs1, float* __restrict__ b1p,
    ushort* __restrict__ U) {
  int bid = blockIdx.x;
  int t = threadIdx.x;
  if (bid < 256) {
    int h = bid;
    __shared__ float sdre[32], sdim[32], scdr[32], scdi[32], slr[32], sli[32];
    if (t < 32) {
      int i = h * 32 + t;
      float dt = expf(log_dt[h]);
      float ar = -expf(log_A_real[i]);
      float ai = A_imag[i];
      float dre = ar * dt, dim = ai * dt;
      float er = expf(dre), sn, cs;
      sincosf(dim, &sn, &cs);
      float lr = er * cs, li = er * sn;
      float nr = lr - 1.f, ni = li;
      float inv = 1.f / (ar * ar + ai * ai);
      float tr = (nr * ar + ni * ai) * inv, ti = (ni * ar - nr * ai) * inv;
      float cdr = C_re[i] * tr - C_im[i] * ti;
      float cdi = C_re[i] * ti + C_im[i] * tr;
      sdre[t] = dre; sdim[t] = dim; scdr[t] = cdr; scdi[t] = cdi;
      slr[t] = lr; sli[t] = li;
      float e1 = expf(128.f * dre), ph = 128.f * dim;
      sincosf(ph, &sn, &cs);
      parK[i] = e1 * cs;
      parK[8192 + i] = e1 * sn;
    }
    __syncthreads();
    if (t < 128) {
      float ksum = 0.f;
      float tf = (float)t;
      for (int n = 0; n < 32; ++n) {
        float e = expf(tf * sdre[n]);
        float sn, cs;
        sincosf(tf * sdim[n], &sn, &cs);
        float pr = e * cs, pi = e * sn;  // lam^t
        ksum = fmaf(scdr[n], pr, fmaf(-scdi[n], pi, ksum));
        Lb[((size_t)h * 64 + 2 * n) * 128 + (127 - t)] = f2bf(pr);
        Lb[((size_t)h * 64 + 2 * n + 1) * 128 + (127 - t)] = f2bf(pi);
        float plr = pr * slr[n] - pi * sli[n];
        float pli = pr * sli[n] + pi * slr[n];  // lam^{t+1}
        Mb[((size_t)h * 128 + t) * 64 + 2 * n] =
            f2bf(2.f * (scdr[n] * plr - scdi[n] * pli));
        Mb[((size_t)h * 128 + t) * 64 + 2 * n + 1] =
            f2bf(-2.f * (scdr[n] * pli + scdi[n] * plr));
      }
      parK[16384 + h * 128 + t] = 2.f * ksum;
    }
  } else if (bid < 576) {
    int wb = bid - 256;
    if (wb < 64) {
      int i = wb * 256 + t;  // 16384 threads
      int mat = i >> 13;
      int fi = i & 8191;  // ((kk*16+g)*64 + l)
      int l = fi & 63;
      int gk = fi >> 6;
      int g = gk & 15, kk = gk >> 4;
      int srow = mat ? ((g >> 2) * 64 + (l & 15) * 4 + (g & 3))
                     : (g * 16 + (l & 15));
      int scol = kk * 32 + ((l >> 4) << 3);
      const float* W = mat ? W2 : W1;
      ushort* out = mat ? w2f : w1f;
      short8 v;
#pragma unroll
      for (int e = 0; e < 8; ++e) {
        float w = W[(size_t)srow * 256 + scol + e];
        if (!mat) w *= gam[scol + e];
        v[e] = (short)f2bf(w);
      }
      *(short8*)&out[(size_t)fi * 8] = v;
    } else {
      int o = wb - 64;
      __shared__ float ra[256], rb[256];
      float w = W1[(size_t)o * 256 + t];
      ra[t] = bf2f(f2bf(w * gam[t]));
      rb[t] = w * bet[t];
      __syncthreads();
      for (int s = 128; s > 0; s >>= 1) {
        if (t < s) { ra[t] += ra[t + s]; rb[t] += rb[t + s]; }
        __syncthreads();
      }
      if (t == 0) { cs1[o] = ra[0]; b1p[o] = b1[o] + rb[0]; }
    }
  } else {
    int blk = bid - 576;  // 2048
    int b = blk >> 7;
    int l0 = (blk & 127) << 5;
    __shared__ float tile[32][257];
#pragma unroll 8
    for (int r = 0; r < 32; ++r)
      tile[r][t] = x[((size_t)b * L_SEQ + l0 + r) * H_DIM + t];
    __syncthreads();
    int hq = t >> 2, ls = (t & 3) * 8;
#pragma unroll
    for (int pass = 0; pass < 4; ++pass) {
      int h = pass * 64 + hq;
      short8 v;
#pragma unroll
      for (int j = 0; j < 8; ++j) v[j] = (short)f2bf(tile[ls + j][h]);
      *(short8*)&U[(size_t)h * 65536 + (size_t)b * L_SEQ + l0 + ls] = v;
    }
  }
}

// FUSED states + scan + y (4-wave round-5/8 version — verified best).
__global__ __launch_bounds__(256, 2) void k_sy(
    const ushort* __restrict__ U, const ushort* __restrict__ Lb,
    const float* __restrict__ parK, const ushort* __restrict__ Mb,
    const float* __restrict__ Dp, ushort* __restrict__ Uo) {
  int wgid = (blockIdx.x & 7) * 128 + (blockIdx.x >> 3);  // bijective, 1024
  int h = wgid >> 2, ct = wgid & 3;
  int t = threadIdx.x;
  int lane = t & 63, wid = t >> 6;
  int wm = wid & 1, wn = wid >> 1;
  int lr_ = lane & 15, lk = (lane >> 4) << 3;
  __shared__ ushort Bt[128][KPAD];                       // U tile, whole kernel
  __shared__ __attribute__((aligned(16))) ushort ovl[18432];  // 36 KiB union
  __shared__ float Krow[128];
  ushort (*sts)[72] = (ushort(*)[72])ovl;                // states (pad-72)
  ushort (*M_lds)[72] = (ushort(*)[72])(ovl + 128 * 72); // M (pad-72)
  ushort (*T_lds)[136] = (ushort(*)[136])ovl;            // phase-2 overlay
  if (t < 128) {
    float kv = parK[16384 + h * 128 + t];
    if (t == 0) kv += Dp[h];
    Krow[t] = kv;
  }
#pragma unroll
  for (int q = 0; q < 8; ++q) {
    int idx = q * 256 + t;
    int cc = idx >> 4, seg = idx & 15;
    int col = ct * 128 + cc;
    int b = col >> 5, c = col & 31;
    *(short8*)&Bt[cc][seg * 8] = *(const short8*)&U[
        (size_t)h * 65536 + (size_t)b * L_SEQ + c * L_C + seg * 8];
  }
#pragma unroll
  for (int q = 0; q < 4; ++q) {
    int idx = q * 256 + t;
    int r = idx >> 3, seg = idx & 7;
    *(short8*)&M_lds[r][seg * 8] =
        *(const short8*)&Mb[((size_t)h * 128 + r) * 64 + seg * 8];
  }
  __syncthreads();
  {
    f32x4 acc2[4][2];
#pragma unroll
    for (int m = 0; m < 4; ++m)
#pragma unroll
      for (int n = 0; n < 2; ++n) acc2[m][n] = (f32x4){0.f, 0.f, 0.f, 0.f};
#pragma unroll
    for (int ks = 0; ks < 4; ++ks) {
      int k0 = ks * 32;
      short8 a[4], bfr[2];
#pragma unroll
      for (int m = 0; m < 4; ++m)
        a[m] = *(const short8*)&Bt[wm * 64 + m * 16 + lr_][k0 + lk];
#pragma unroll
      for (int n = 0; n < 2; ++n)
        bfr[n] = *(const short8*)&Lb[
            ((size_t)h * 64 + wn * 32 + n * 16 + lr_) * 128 + k0 + lk];
#pragma unroll
      for (int m = 0; m < 4; ++m)
#pragma unroll
        for (int n = 0; n < 2; ++n)
          acc2[m][n] = __builtin_amdgcn_mfma_f32_16x16x32_bf16(
              a[m], bfr[n], acc2[m][n], 0, 0, 0);
    }
#pragma unroll
    for (int m = 0; m < 4; ++m)
#pragma unroll
      for (int n = 0; n < 2; ++n)
#pragma unroll
        for (int jj = 0; jj < 4; ++jj) {
          int rowl = wm * 64 + m * 16 + (lane >> 4) * 4 + jj;  // local 0..127
          int col2n = wn * 32 + n * 16 + (lane & 15);
          sts[rowl][col2n] = f2bf(acc2[m][n][jj]);
        }
  }
  __syncthreads();
  if (t < 128) {
    int n = t & 31, bl = t >> 5;  // local batch 0..3
    float Lr = parK[h * 32 + n], Li = parK[8192 + h * 32 + n];
    float cr = 0.f, ci = 0.f;
#pragma unroll
    for (int c = 0; c < N_C; ++c) {
      int rowl = bl * 32 + c;
      uint* p = (uint*)&sts[rowl][2 * n];
      uint v = *p;
      float fr = bf2f((ushort)(v & 0xffff));
      float fi = bf2f((ushort)(v >> 16));
      *p = (uint)f2bf(cr) | ((uint)f2bf(ci) << 16);
      float nr_ = fmaf(Lr, cr, fmaf(-Li, ci, fr));
      float ni_ = fmaf(Lr, ci, fmaf(Li, cr, fi));
      cr = nr_; ci = ni_;
    }
  }
  __syncthreads();
  f32x4 acc[4][4];
#pragma unroll
  for (int m = 0; m < 4; ++m)
#pragma unroll
    for (int n = 0; n < 4; ++n) acc[m][n] = (f32x4){0.f, 0.f, 0.f, 0.f};
#pragma unroll
  for (int ks = 0; ks < 2; ++ks) {
    int k0 = ks * 32;
    short8 a[4], bfr[4];
#pragma unroll
    for (int m = 0; m < 4; ++m)
      a[m] = *(const short8*)&sts[wm * 64 + m * 16 + lr_][k0 + lk];
#pragma unroll
    for (int n = 0; n < 4; ++n)
      bfr[n] = *(const short8*)&M_lds[wn * 64 + n * 16 + lr_][k0 + lk];
#pragma unroll
    for (int m = 0; m < 4; ++m)
#pragma unroll
      for (int n = 0; n < 4; ++n)
        acc[m][n] = __builtin_amdgcn_mfma_f32_16x16x32_bf16(a[m], bfr[n],
                                                            acc[m][n], 0, 0, 0);
  }
  __syncthreads();  // sts + M dead; T overlays
#pragma unroll
  for (int q = 0; q < 8; ++q) {
    int idx = q * 256 + t;
    int r = idx >> 4, seg = idx & 15;
    short8 v;
#pragma unroll
    for (int e = 0; e < 8; ++e) {
      int d = r - (seg * 8 + e);
      float f = (d >= 0) ? Krow[d] : 0.f;
      v[e] = (short)f2bf(f);
    }
    *(short8*)&T_lds[r][seg * 8] = v;
  }
  __syncthreads();
#pragma unroll
  for (int ks = 0; ks < 4; ++ks) {
    int k0 = ks * 32;
    short8 a[4], bfr[4];
#pragma unroll
    for (int m = 0; m < 4; ++m)
      a[m] = *(const short8*)&Bt[wm * 64 + m * 16 + lr_][k0 + lk];
#pragma unroll
    for (int n = 0; n < 4; ++n)
      bfr[n] = *(const short8*)&T_lds[wn * 64 + n * 16 + lr_][k0 + lk];
#pragma unroll
    for (int m = 0; m < 4; ++m)
#pragma unroll
      for (int n = 0; n < 4; ++n)
        acc[m][n] = __builtin_amdgcn_mfma_f32_16x16x32_bf16(a[m], bfr[n],
                                                            acc[m][n], 0, 0, 0);
  }
  __syncthreads();
#pragma unroll
  for (int m = 0; m < 4; ++m) {
    int rowl = wm * 64 + m * 16 + (lane >> 4) * 4;
#pragma unroll
    for (int jj = 0; jj < 4; ++jj) {
      int row = rowl + jj;
#pragma unroll
      for (int n = 0; n < 4; ++n) {
        int lp = wn * 64 + n * 16 + (lane & 15);
        Bt[row][lp] = f2bf(acc[m][n][jj]);
      }
    }
  }
  __syncthreads();
#pragma unroll
  for (int q = 0; q < 8; ++q) {
    int idx = q * 256 + t;
    int r = idx >> 4, seg = idx & 15;
    int col = ct * 128 + r;
    int b = col >> 5, c = col & 31;
    *(short8*)&Uo[(size_t)h * 65536 + (size_t)b * L_SEQ + c * L_C + seg * 8] =
        *(const short8*)&Bt[r][seg * 8];
  }
}

// Fused LN + MLP — round-5 version (measured 48.0 us, banked). Unchanged.
__global__ __launch_bounds__(512, 4) void k_mlp(
    const ushort* __restrict__ U, const ushort* __restrict__ w1f,
    const ushort* __restrict__ w2f, const float* __restrict__ cs1,
    const float* __restrict__ b1p, const float* __restrict__ b2,
    const float* __restrict__ xres, float* __restrict__ outp) {
  int m0 = blockIdx.x << 7;  // 512 blocks x 128 rows of (B*L)
  int t = threadIdx.x;       // 512 threads = 8 waves (2M x 4N)
  int lane = t & 63, wid = t >> 6;
  int wm = wid & 1, wn = wid >> 1;
  int lr_ = lane & 15, lk = (lane >> 4) << 3;
  __shared__ ushort smem[33792];  // yt[128][264] swizzled; c_s overlays [0,32768)
  __shared__ float redA[128][4], redB[128][4];
  __shared__ float mu_s[128], rs_s[128];
  // ---- transpose load: U[h][m0+m] -> yt[m][h ^ ((m>>3&7)<<3)] ----
  {
    int hseg = t >> 4, l16 = t & 15;
    int sw = (l16 & 7) << 3;
#pragma unroll
    for (int p = 0; p < 8; ++p) {
      int h = p * 32 + hseg;
      short8 v = *(const short8*)&U[(size_t)h * 65536 + m0 + l16 * 8];
      int hx = h ^ sw;
#pragma unroll
      for (int e = 0; e < 8; ++e)
        smem[(l16 * 8 + e) * 264 + hx] = (ushort)v[e];
    }
  }
  __syncthreads();
  // ---- LN stats ----
  {
    int rl = t >> 2, q = (t & 3) << 6;
    float s = 0.f, s2 = 0.f;
#pragma unroll
    for (int e = 0; e < 64; e += 8) {
      short8 v = *(const short8*)&smem[rl * 264 + q + e];
#pragma unroll
      for (int j = 0; j < 8; ++j) {
        float f = bf2f((ushort)v[j]);
        s += f;
        s2 = fmaf(f, f, s2);
      }
    }
    redA[rl][t & 3] = s;
    redB[rl][t & 3] = s2;
  }
  __syncthreads();
  if (t < 128) {
    float ss = redA[t][0] + redA[t][1] + redA[t][2] + redA[t][3];
    float ss2 = redB[t][0] + redB[t][1] + redB[t][2] + redB[t][3];
    float mu = ss * (1.f / 256.f);
    float var = fmaf(ss2, 1.f / 256.f, -mu * mu);
    mu_s[t] = mu;
    rs_s[t] = rsqrtf(var + 1e-5f);
  }
  __syncthreads();
  // ---- phase 1: acc = y @ (W1*g)^T ----
  f32x4 acc[4][4];
#pragma unroll
  for (int m = 0; m < 4; ++m)
#pragma unroll
    for (int n = 0; n < 4; ++n) acc[m][n] = (f32x4){0.f, 0.f, 0.f, 0.f};
#pragma unroll
  for (int kabs = 0; kabs < 8; ++kabs) {
    short8 af[4], bfr[4];
#pragma unroll
    for (int n = 0; n < 4; ++n)
      bfr[n] = *(const short8*)&w1f[(((size_t)kabs * 16 + wn * 4 + n) * 64 +
                                     lane) * 8];
#pragma unroll
    for (int m = 0; m < 4; ++m) {
      int row = wm * 64 + m * 16 + lr_;
      int sw = ((row >> 3) & 7) << 3;
      af[m] = *(const short8*)&smem[row * 264 + ((kabs * 32 + lk) ^ sw)];
    }
#pragma unroll
    for (int m = 0; m < 4; ++m)
#pragma unroll
      for (int n = 0; n < 4; ++n)
        acc[m][n] = __builtin_amdgcn_mfma_f32_16x16x32_bf16(af[m], bfr[n],
                                                            acc[m][n], 0, 0, 0);
  }
  __syncthreads();  // yt dead; c_s overlays
  // ---- epilogue 1: LN-correct + bias + relu -> bf16 -> swizzled c_s ----
  int prow = (lane >> 4) << 2;
  int pcol = lane & 15;
#pragma unroll
  for (int n = 0; n < 4; ++n) {
    int gcol = wn * 64 + n * 16 + pcol;
    float c1v = cs1[gcol], b1v = b1p[gcol];
#pragma unroll
    for (int m = 0; m < 4; ++m) {
      int rbase = wm * 64 + m * 16 + prow;
#pragma unroll
      for (int j = 0; j < 4; ++j) {
        int row = rbase + j;
        float v = fmaxf(
            fmaf(rs_s[row], acc[m][n][j] - mu_s[row] * c1v, b1v), 0.f);
        int byte = ((row << 9) + (gcol << 1)) ^ ((row & 7) << 4);
        smem[byte >> 1] = f2bf(v);
        acc[m][n][j] = 0.f;  // re-zero for phase 2
      }
    }
  }
  __syncthreads();
  // ---- phase 2: acc = C1 @ W2^T (W2 output cols permuted at pack time) ----
#pragma unroll
  for (int kabs = 0; kabs < 8; ++kabs) {
    short8 af[4], bfr[4];
#pragma unroll
    for (int n = 0; n < 4; ++n)
      bfr[n] = *(const short8*)&w2f[(((size_t)kabs * 16 + wn * 4 + n) * 64 +
                                     lane) * 8];
#pragma unroll
    for (int m = 0; m < 4; ++m) {
      int row = wm * 64 + m * 16 + lr_;
      int byte = ((row << 9) + ((kabs * 32 + lk) << 1)) ^ ((row & 7) << 4);
      af[m] = *(const short8*)&smem[byte >> 1];
    }
#pragma unroll
    for (int m = 0; m < 4; ++m)
#pragma unroll
      for (int n = 0; n < 4; ++n)
        acc[m][n] = __builtin_amdgcn_mfma_f32_16x16x32_bf16(af[m], bfr[n],
                                                            acc[m][n], 0, 0, 0);
  }
  // ---- epilogue 2: lane owns cols wn*64 + pcol*4 + {0..3} -> float4 IO ----
  f32x4 bv2q = *(const f32x4*)&b2[wn * 64 + pcol * 4];
#pragma unroll
  for (int m = 0; m < 4; ++m) {
#pragma unroll
    for (int j = 0; j < 4; ++j) {
      int grow = m0 + wm * 64 + m * 16 + prow + j;
      size_t base = (size_t)grow * 256 + wn * 64 + pcol * 4;
      f32x4 xr = *(const f32x4*)&xres[base];
      f32x4 o;
#pragma unroll
      for (int n = 0; n < 4; ++n)
        o[n] = xr[n] + fmaxf(acc[m][n][j] + bv2q[n], 0.f);
      *(f32x4*)&outp[base] = o;
    }
  }
}

extern "C" void kernel_launch(void* const* d_in, const int* in_sizes, int n_in,
                              void* d_out, int out_size, void* d_ws, size_t ws_size,
                              hipStream_t stream) {
  const float* x          = (const float*)d_in[0];
  const float* log_dt     = (const float*)d_in[1];
  const float* log_A_real = (const float*)d_in[2];
  const float* A_imag     = (const float*)d_in[3];
  const float* C_re       = (const float*)d_in[4];
  const float* C_im       = (const float*)d_in[5];
  const float* Dp         = (const float*)d_in[6];
  const float* ln_g       = (const float*)d_in[7];
  const float* ln_b       = (const float*)d_in[8];
  const float* W1         = (const float*)d_in[9];
  const float* b1         = (const float*)d_in[10];
  const float* W2         = (const float*)d_in[11];
  const float* b2         = (const float*)d_in[12];

  char* ws = (char*)d_ws;
  float* parK = (float*)ws;                       // 192 KiB
  float* cs1  = (float*)(ws + 0x30000);           // 1 KiB
  float* b1p  = (float*)(ws + 0x30400);           // 1 KiB
  ushort* w1f = (ushort*)(ws + 0x40000);          // 128 KiB (fragment order)
  ushort* w2f = (ushort*)(ws + 0x60000);          // 128 KiB (fragment order)
  ushort* Mb  = (ushort*)(ws + 0x80000);          // 4 MiB
  ushort* Lb  = (ushort*)(ws + 0x480000);         // 4 MiB
  ushort* U   = (ushort*)(ws + 0x2080000);        // 32 MiB (y written in place)

  k_front<<<2624, 256, 0, stream>>>(x, log_dt, log_A_real, A_imag, C_re, C_im,
                                    W1, W2, ln_g, ln_b, b1, parK, Mb, Lb,
                                    w1f, w2f, cs1, b1p, U);
  k_sy<<<1024, 256, 0, stream>>>(U, Lb, parK, Mb, Dp, U);
  k_mlp<<<512, 512, 0, stream>>>(U, w1f, w2f, cs1, b1p, b2, x,
                                 (float*)d_out);
}